// Round 4
// baseline (30123.956 us; speedup 1.0000x reference)
//
#include <hip/hip_runtime.h>
#include <stdint.h>

#define ZD 41
#define YD 1600
#define XD 1408
#define YXD (YD * XD)
#define NKEYS (ZD * YD * XD)          // 92,364,800 linear sites
#define BM_WORDS ((NKEYS + 63) / 64)  // 1,443,200 u64 words (exact: NKEYS%64==0)
#define BN_EPS 1e-3f

typedef unsigned long long u64;

// ---------------- ws layout (no init kernel, no atomics anywhere) ----------
// [0,128)                 accum: [0..15]=sum, [16..31]=sumsq (written by finalize)
// [128, +BM_WORDS*4)      prefix[w] = # active keys with key < w*64
// [.., +BM_WORDS*8)       bitmap (u64 per 64 sites)
// [+8]                    pad for bitmap[BM_WORDS] speculative read
// [then, +nb*32*4)        per-block BN partials: [bid][0..15]=sum,[16..31]=sumsq
// OOB-by-one reads: bitmap[-1] -> last prefix words (in-ws, masked out),
// bitmap[BM_WORDS] -> pad. All safe.

// Build bitmap + rank-prefix with NO atomics: keys are sorted ascending
// (np.unique), so thread i leads its 64-key word iff word(key[i-1]) differs.
// Leaders OR their word-mates' bits (consecutive threads) and fill the gap
// words to their left — every word written exactly once, plain stores.
__global__ void __launch_bounds__(256) build_index(
    const int4* __restrict__ coords, uint32_t* __restrict__ prefix,
    u64* __restrict__ bitmap, int n) {
  int i = blockIdx.x * blockDim.x + threadIdx.x;
  if (i >= n) return;
  int4 c = coords[i];  // (0, z, y, x)
  int key = (c.y * YD + c.z) * XD + c.w;
  int w = key >> 6;
  int pw = -1;
  if (i > 0) {
    int4 cp = coords[i - 1];
    pw = ((cp.y * YD + cp.z) * XD + cp.w) >> 6;
  }
  if (w != pw) {  // leader
    for (int g = pw + 1; g < w; ++g) {  // gap fill (avg ~3.6 words)
      bitmap[g] = 0ull;
      prefix[g] = (uint32_t)i;
    }
    u64 bits = 1ull << (key & 63);
    int j = i + 1;
    while (j < n) {  // consecutive threads sharing my word (rare at 0.43%)
      int4 cj = coords[j];
      int kj = (cj.y * YD + cj.z) * XD + cj.w;
      if ((kj >> 6) != w) break;
      bits |= 1ull << (kj & 63);
      ++j;
    }
    bitmap[w] = bits;
    prefix[w] = (uint32_t)i;
  }
  if (i == n - 1) {  // tail fill
    for (int g = w + 1; g < BM_WORDS; ++g) {
      bitmap[g] = 0ull;
      prefix[g] = (uint32_t)n;
    }
  }
}

__global__ void __launch_bounds__(256) subm_conv(
    const float4* __restrict__ feats, const int4* __restrict__ coords,
    const float* __restrict__ weight, const uint32_t* __restrict__ prefix,
    const u64* __restrict__ bitmap, float* __restrict__ out,
    float* __restrict__ partial, int n) {
  __shared__ float wl[27 * 64];  // [k][c][o] = k*64 + c*16 + o
  __shared__ float sw[4][32];
  for (int t = threadIdx.x; t < 27 * 64; t += 256) wl[t] = weight[t];
  __syncthreads();

  // Bijective XCD-chunk swizzle: contiguous voxel ranges per XCD so the
  // sorted-key bitmap+prefix slice (~2.2MB) stays in the per-XCD 4MB L2.
  int B = gridDim.x;
  int q = B >> 3, r = B & 7;
  int xcd = blockIdx.x & 7, off = blockIdx.x >> 3;
  int sb = (xcd < r ? xcd * (q + 1) : r * (q + 1) + (xcd - r) * q) + off;
  int i = sb * 256 + (int)threadIdx.x;

  float acc[16];
#pragma unroll
  for (int o = 0; o < 16; o++) acc[o] = 0.f;

  if (i < n) {  // no early return: all threads join the BN epilogue
    int4 czyx = coords[i];
    int z = czyx.y, y = czyx.z, x = czyx.w;
    int key = (z * YD + y) * XD + x;

#pragma unroll
    for (int dz = -1; dz <= 1; dz++) {
      if ((unsigned)(z + dz) >= (unsigned)ZD) continue;
#pragma unroll
      for (int dy = -1; dy <= 1; dy++) {
        if ((unsigned)(y + dy) >= (unsigned)YD) continue;
        int nb = key + dz * YXD + dy * XD;  // dx = 0 neighbor key
        int base = nb - 1;
        int w0i = base >> 6;  // arithmetic shift: base=-1 -> -1 (safe read)
        u64 w0 = bitmap[w0i];
        u64 w1 = bitmap[w0i + 1];
        unsigned p = (unsigned)(base & 63);
        u64 win = (w0 >> p) | (p ? (w1 << (64 - p)) : 0ull);
        unsigned m = (unsigned)win & 7u;
        if (x == 0) m &= 6u;
        if (x == XD - 1) m &= 3u;
        if (!m) continue;
        uint32_t pre0 = prefix[w0i];      // lazy: only on hit (~1.11/voxel)
        uint32_t pre1 = prefix[w0i + 1];  // adjacent, L2-resident
        do {
          int b = __ffs(m) - 1;  // 0,1,2 -> dx = b-1
          m &= m - 1;
          int nk = base + b;
          int wi = nk >> 6;
          u64 word = (wi == w0i) ? w0 : w1;
          uint32_t pre = (wi == w0i) ? pre0 : pre1;
          int j = (int)pre + __popcll(word & ((1ull << (nk & 63)) - 1ull));
          float4 f = feats[j];
          const float* wp = &wl[((dz + 1) * 9 + (dy + 1) * 3 + b) * 64];
#pragma unroll
          for (int o = 0; o < 16; o++)
            acc[o] += f.x * wp[o] + f.y * wp[o + 16] + f.z * wp[o + 32] +
                      f.w * wp[o + 48];
        } while (m);
      }
    }

    float4* o4 = (float4*)(out + (size_t)i * 16);
    o4[0] = make_float4(acc[0], acc[1], acc[2], acc[3]);
    o4[1] = make_float4(acc[4], acc[5], acc[6], acc[7]);
    o4[2] = make_float4(acc[8], acc[9], acc[10], acc[11]);
    o4[3] = make_float4(acc[12], acc[13], acc[14], acc[15]);
  }

  // Fused BN partial reduction (inactive threads contribute acc==0).
  int lane = threadIdx.x & 63, wv = threadIdx.x >> 6;
#pragma unroll
  for (int o = 0; o < 16; o++) {
    float s = acc[o], qq = acc[o] * acc[o];
#pragma unroll
    for (int offx = 32; offx; offx >>= 1) {
      s += __shfl_xor(s, offx);
      qq += __shfl_xor(qq, offx);
    }
    if (lane == 0) {
      sw[wv][o] = s;
      sw[wv][16 + o] = qq;
    }
  }
  __syncthreads();
  if (threadIdx.x < 32) {
    float v = sw[0][threadIdx.x] + sw[1][threadIdx.x] + sw[2][threadIdx.x] +
              sw[3][threadIdx.x];
    partial[(size_t)blockIdx.x * 32 + threadIdx.x] = v;
  }
}

// Single block sums the per-block partials into accum (plain stores).
__global__ void __launch_bounds__(256) bn_finalize(
    const float* __restrict__ partial, float* __restrict__ accum, int nb) {
  __shared__ float s[256];
  int t = threadIdx.x;
  int c = t & 31;
  float v = 0.f;
  for (int b = t >> 5; b < nb; b += 8) v += partial[(size_t)b * 32 + c];
  s[t] = v;
  __syncthreads();
  if (t < 128) s[t] += s[t + 128];
  __syncthreads();
  if (t < 64) s[t] += s[t + 64];
  __syncthreads();
  if (t < 32) accum[t] = s[t] + s[t + 32];
}

__global__ void __launch_bounds__(256) bn_apply(
    float* __restrict__ out, const float* __restrict__ accum,
    const float* __restrict__ gamma, const float* __restrict__ beta, int n4,
    float invN) {
  __shared__ float sa[16], sb[16];
  int t = threadIdx.x;
  if (t < 16) {
    float mu = accum[t] * invN;
    float var = accum[16 + t] * invN - mu * mu;
    float inv = rsqrtf(var + BN_EPS);
    float a = gamma[t] * inv;
    sa[t] = a;
    sb[t] = beta[t] - mu * a;
  }
  __syncthreads();
  int i = blockIdx.x * 256 + t;
  if (i >= n4) return;
  float4* p = (float4*)out;
  float4 v = p[i];
  int c0 = (i & 3) * 4;
  v.x = fmaxf(v.x * sa[c0 + 0] + sb[c0 + 0], 0.f);
  v.y = fmaxf(v.y * sa[c0 + 1] + sb[c0 + 1], 0.f);
  v.z = fmaxf(v.z * sa[c0 + 2] + sb[c0 + 2], 0.f);
  v.w = fmaxf(v.w * sa[c0 + 3] + sb[c0 + 3], 0.f);
  p[i] = v;
}

extern "C" void kernel_launch(void* const* d_in, const int* in_sizes, int n_in,
                              void* d_out, int out_size, void* d_ws,
                              size_t ws_size, hipStream_t stream) {
  const float4* feats = (const float4*)d_in[0];
  const int4* coords = (const int4*)d_in[1];
  const float* weight = (const float*)d_in[2];
  const float* gamma = (const float*)d_in[3];
  const float* beta = (const float*)d_in[4];
  int n = in_sizes[0] / 4;

  float* accum = (float*)d_ws;
  uint32_t* prefix = (uint32_t*)((char*)d_ws + 128);
  u64* bitmap = (u64*)((char*)d_ws + 128 + (size_t)BM_WORDS * 4);
  float* partial =
      (float*)((char*)d_ws + 128 + (size_t)BM_WORDS * 4 + (size_t)BM_WORDS * 8 + 8);

  int bb = (n + 255) / 256;
  hipLaunchKernelGGL(build_index, dim3(bb), dim3(256), 0, stream, coords,
                     prefix, bitmap, n);
  hipLaunchKernelGGL(subm_conv, dim3(bb), dim3(256), 0, stream, feats, coords,
                     weight, prefix, bitmap, (float*)d_out, partial, n);
  hipLaunchKernelGGL(bn_finalize, dim3(1), dim3(256), 0, stream, partial,
                     accum, bb);
  int n4 = n * 4;
  hipLaunchKernelGGL(bn_apply, dim3((n4 + 255) / 256), dim3(256), 0, stream,
                     (float*)d_out, accum, gamma, beta, n4, 1.0f / n);
}

// Round 5
// 173.484 us; speedup vs baseline: 173.6406x; 173.6406x over previous
//
#include <hip/hip_runtime.h>
#include <stdint.h>

#define ZD 41
#define YD 1600
#define XD 1408
#define YXD (YD * XD)
#define NKEYS (ZD * YD * XD)          // 92,364,800 linear sites
#define BM_WORDS ((NKEYS + 63) / 64)  // 1,443,200 u64 words (exact: NKEYS%64==0)
#define BN_EPS 1e-3f

typedef unsigned long long u64;

// ---------------- ws layout (no init kernel, no atomics anywhere) ----------
// [0,128)                 accum: [0..15]=sum, [16..31]=sumsq (written by finalize)
// [128, +BM_WORDS*4)      prefix[w] = # active keys with key < w*64
// [.., +BM_WORDS*8)       bitmap (u64 per 64 sites)
// [+8]                    pad for bitmap[BM_WORDS] speculative read
// [then, +nb*32*4)        per-block BN partials: [bid][0..15]=sum,[16..31]=sumsq
// OOB-by-one reads: bitmap[-1] -> last prefix words (in-ws, masked out),
// bitmap[BM_WORDS] -> pad. All safe.

// Build bitmap + rank-prefix with NO atomics: keys are sorted ascending
// (np.unique), so thread i leads its 64-key word iff word(key[i-1]) differs.
// Leaders OR their word-mates' bits (consecutive threads) and fill the gap
// words to their left — every word written exactly once, plain stores.
// Tail region past the max key (large: np.unique(raw)[:N] truncation means
// max key ~31M of 92M) is filled GRID-STRIDE by all threads — the R4 bug
// was a single-threaded ~958k-word tail loop (30+ ms).
__global__ void __launch_bounds__(256) build_index(
    const int4* __restrict__ coords, uint32_t* __restrict__ prefix,
    u64* __restrict__ bitmap, int n) {
  int i = blockIdx.x * blockDim.x + threadIdx.x;

  // Parallel tail fill: all threads read the last (max) key — L2 broadcast.
  {
    int4 cl = coords[n - 1];
    int wlast = ((cl.y * YD + cl.z) * XD + cl.w) >> 6;
    int stride = gridDim.x * blockDim.x;
    for (int g = wlast + 1 + i; g < BM_WORDS; g += stride) {
      bitmap[g] = 0ull;
      prefix[g] = (uint32_t)n;
    }
  }

  if (i >= n) return;
  int4 c = coords[i];  // (0, z, y, x)
  int key = (c.y * YD + c.z) * XD + c.w;
  int w = key >> 6;
  int pw = -1;
  if (i > 0) {
    int4 cp = coords[i - 1];
    pw = ((cp.y * YD + cp.z) * XD + cp.w) >> 6;
  }
  if (w != pw) {  // leader
    for (int g = pw + 1; g < w; ++g) {  // gap fill (avg ~1.2 words)
      bitmap[g] = 0ull;
      prefix[g] = (uint32_t)i;
    }
    u64 bits = 1ull << (key & 63);
    int j = i + 1;
    while (j < n) {  // consecutive threads sharing my word (rare at this density)
      int4 cj = coords[j];
      int kj = (cj.y * YD + cj.z) * XD + cj.w;
      if ((kj >> 6) != w) break;
      bits |= 1ull << (kj & 63);
      ++j;
    }
    bitmap[w] = bits;
    prefix[w] = (uint32_t)i;
  }
}

__global__ void __launch_bounds__(256) subm_conv(
    const float4* __restrict__ feats, const int4* __restrict__ coords,
    const float* __restrict__ weight, const uint32_t* __restrict__ prefix,
    const u64* __restrict__ bitmap, float* __restrict__ out,
    float* __restrict__ partial, int n) {
  __shared__ float wl[27 * 64];  // [k][c][o] = k*64 + c*16 + o
  __shared__ float sw[4][32];
  for (int t = threadIdx.x; t < 27 * 64; t += 256) wl[t] = weight[t];
  __syncthreads();

  // Bijective XCD-chunk swizzle: contiguous voxel ranges per XCD so the
  // sorted-key bitmap+prefix slice (~2.2MB) stays in the per-XCD 4MB L2.
  int B = gridDim.x;
  int q = B >> 3, r = B & 7;
  int xcd = blockIdx.x & 7, off = blockIdx.x >> 3;
  int sb = (xcd < r ? xcd * (q + 1) : r * (q + 1) + (xcd - r) * q) + off;
  int i = sb * 256 + (int)threadIdx.x;

  float acc[16];
#pragma unroll
  for (int o = 0; o < 16; o++) acc[o] = 0.f;

  if (i < n) {  // no early return: all threads join the BN epilogue
    int4 czyx = coords[i];
    int z = czyx.y, y = czyx.z, x = czyx.w;
    int key = (z * YD + y) * XD + x;

#pragma unroll
    for (int dz = -1; dz <= 1; dz++) {
      if ((unsigned)(z + dz) >= (unsigned)ZD) continue;
#pragma unroll
      for (int dy = -1; dy <= 1; dy++) {
        if ((unsigned)(y + dy) >= (unsigned)YD) continue;
        int nb = key + dz * YXD + dy * XD;  // dx = 0 neighbor key
        int base = nb - 1;
        int w0i = base >> 6;  // arithmetic shift: base=-1 -> -1 (safe read)
        u64 w0 = bitmap[w0i];
        u64 w1 = bitmap[w0i + 1];
        unsigned p = (unsigned)(base & 63);
        u64 win = (w0 >> p) | (p ? (w1 << (64 - p)) : 0ull);
        unsigned m = (unsigned)win & 7u;
        if (x == 0) m &= 6u;
        if (x == XD - 1) m &= 3u;
        if (!m) continue;
        uint32_t pre0 = prefix[w0i];      // lazy: only on hit (~1.11/voxel)
        uint32_t pre1 = prefix[w0i + 1];  // adjacent, L2-resident
        do {
          int b = __ffs(m) - 1;  // 0,1,2 -> dx = b-1
          m &= m - 1;
          int nk = base + b;
          int wi = nk >> 6;
          u64 word = (wi == w0i) ? w0 : w1;
          uint32_t pre = (wi == w0i) ? pre0 : pre1;
          int j = (int)pre + __popcll(word & ((1ull << (nk & 63)) - 1ull));
          float4 f = feats[j];
          const float* wp = &wl[((dz + 1) * 9 + (dy + 1) * 3 + b) * 64];
#pragma unroll
          for (int o = 0; o < 16; o++)
            acc[o] += f.x * wp[o] + f.y * wp[o + 16] + f.z * wp[o + 32] +
                      f.w * wp[o + 48];
        } while (m);
      }
    }

    float4* o4 = (float4*)(out + (size_t)i * 16);
    o4[0] = make_float4(acc[0], acc[1], acc[2], acc[3]);
    o4[1] = make_float4(acc[4], acc[5], acc[6], acc[7]);
    o4[2] = make_float4(acc[8], acc[9], acc[10], acc[11]);
    o4[3] = make_float4(acc[12], acc[13], acc[14], acc[15]);
  }

  // Fused BN partial reduction (inactive threads contribute acc==0).
  int lane = threadIdx.x & 63, wv = threadIdx.x >> 6;
#pragma unroll
  for (int o = 0; o < 16; o++) {
    float s = acc[o], qq = acc[o] * acc[o];
#pragma unroll
    for (int offx = 32; offx; offx >>= 1) {
      s += __shfl_xor(s, offx);
      qq += __shfl_xor(qq, offx);
    }
    if (lane == 0) {
      sw[wv][o] = s;
      sw[wv][16 + o] = qq;
    }
  }
  __syncthreads();
  if (threadIdx.x < 32) {
    float v = sw[0][threadIdx.x] + sw[1][threadIdx.x] + sw[2][threadIdx.x] +
              sw[3][threadIdx.x];
    partial[(size_t)blockIdx.x * 32 + threadIdx.x] = v;
  }
}

// Single block sums the per-block partials into accum (plain stores).
__global__ void __launch_bounds__(256) bn_finalize(
    const float* __restrict__ partial, float* __restrict__ accum, int nb) {
  __shared__ float s[256];
  int t = threadIdx.x;
  int c = t & 31;
  float v = 0.f;
  for (int b = t >> 5; b < nb; b += 8) v += partial[(size_t)b * 32 + c];
  s[t] = v;
  __syncthreads();
  if (t < 128) s[t] += s[t + 128];
  __syncthreads();
  if (t < 64) s[t] += s[t + 64];
  __syncthreads();
  if (t < 32) accum[t] = s[t] + s[t + 32];
}

__global__ void __launch_bounds__(256) bn_apply(
    float* __restrict__ out, const float* __restrict__ accum,
    const float* __restrict__ gamma, const float* __restrict__ beta, int n4,
    float invN) {
  __shared__ float sa[16], sb[16];
  int t = threadIdx.x;
  if (t < 16) {
    float mu = accum[t] * invN;
    float var = accum[16 + t] * invN - mu * mu;
    float inv = rsqrtf(var + BN_EPS);
    float a = gamma[t] * inv;
    sa[t] = a;
    sb[t] = beta[t] - mu * a;
  }
  __syncthreads();
  int i = blockIdx.x * 256 + t;
  if (i >= n4) return;
  float4* p = (float4*)out;
  float4 v = p[i];
  int c0 = (i & 3) * 4;
  v.x = fmaxf(v.x * sa[c0 + 0] + sb[c0 + 0], 0.f);
  v.y = fmaxf(v.y * sa[c0 + 1] + sb[c0 + 1], 0.f);
  v.z = fmaxf(v.z * sa[c0 + 2] + sb[c0 + 2], 0.f);
  v.w = fmaxf(v.w * sa[c0 + 3] + sb[c0 + 3], 0.f);
  p[i] = v;
}

extern "C" void kernel_launch(void* const* d_in, const int* in_sizes, int n_in,
                              void* d_out, int out_size, void* d_ws,
                              size_t ws_size, hipStream_t stream) {
  const float4* feats = (const float4*)d_in[0];
  const int4* coords = (const int4*)d_in[1];
  const float* weight = (const float*)d_in[2];
  const float* gamma = (const float*)d_in[3];
  const float* beta = (const float*)d_in[4];
  int n = in_sizes[0] / 4;

  float* accum = (float*)d_ws;
  uint32_t* prefix = (uint32_t*)((char*)d_ws + 128);
  u64* bitmap = (u64*)((char*)d_ws + 128 + (size_t)BM_WORDS * 4);
  float* partial =
      (float*)((char*)d_ws + 128 + (size_t)BM_WORDS * 4 + (size_t)BM_WORDS * 8 + 8);

  int bb = (n + 255) / 256;
  hipLaunchKernelGGL(build_index, dim3(bb), dim3(256), 0, stream, coords,
                     prefix, bitmap, n);
  hipLaunchKernelGGL(subm_conv, dim3(bb), dim3(256), 0, stream, feats, coords,
                     weight, prefix, bitmap, (float*)d_out, partial, n);
  hipLaunchKernelGGL(bn_finalize, dim3(1), dim3(256), 0, stream, partial,
                     accum, bb);
  int n4 = n * 4;
  hipLaunchKernelGGL(bn_apply, dim3((n4 + 255) / 256), dim3(256), 0, stream,
                     (float*)d_out, accum, gamma, beta, n4, 1.0f / n);
}

// Round 7
// 129.465 us; speedup vs baseline: 232.6803x; 1.3400x over previous
//
#include <hip/hip_runtime.h>
#include <stdint.h>

#define ZD 41
#define YD 1600
#define XD 1408
#define YXD (YD * XD)
#define NKEYS (ZD * YD * XD)          // 92,364,800 linear sites
#define BM_WORDS ((NKEYS + 63) / 64)  // 1,443,200 u64 words (exact: NKEYS%64==0)
#define BN_EPS 1e-3f

typedef unsigned long long u64;

// ---------------- ws layout (no init kernel, no atomics anywhere) ----------
// [0,128)                 accum: [0..15]=sum, [16..31]=sumsq (written by finalize)
// [128, +BM_WORDS*4)      prefix[w] = # active keys with key < w*64
// [.., +BM_WORDS*8)       bitmap (u64 per 64 sites)
// [+8]                    pad for bitmap[BM_WORDS] speculative read
// [then, +nb*32*4)        per-block BN partials: [bid][0..15]=sum,[16..31]=sumsq
// OOB-by-one reads: bitmap[-1] -> last prefix words (in-ws, masked out),
// bitmap[BM_WORDS] -> pad. All safe.

// Build bitmap + rank-prefix with NO atomics: keys are sorted ascending
// (np.unique), so thread i leads its 64-key word iff word(key[i-1]) differs.
// Leaders OR their word-mates' bits (consecutive threads) and fill the gap
// words to their left — every word written exactly once, plain stores.
// Tail region past the max key is filled GRID-STRIDE (R4 lesson: the
// single-threaded tail loop was 30 ms).
__global__ void __launch_bounds__(256) build_index(
    const int4* __restrict__ coords, uint32_t* __restrict__ prefix,
    u64* __restrict__ bitmap, int n) {
  int i = blockIdx.x * blockDim.x + threadIdx.x;

  // Parallel tail fill: all threads read the last (max) key — L2 broadcast.
  {
    int4 cl = coords[n - 1];
    int wlast = ((cl.y * YD + cl.z) * XD + cl.w) >> 6;
    int stride = gridDim.x * blockDim.x;
    for (int g = wlast + 1 + i; g < BM_WORDS; g += stride) {
      bitmap[g] = 0ull;
      prefix[g] = (uint32_t)n;
    }
  }

  if (i >= n) return;
  int4 c = coords[i];  // (0, z, y, x)
  int key = (c.y * YD + c.z) * XD + c.w;
  int w = key >> 6;
  int pw = -1;
  if (i > 0) {
    int4 cp = coords[i - 1];
    pw = ((cp.y * YD + cp.z) * XD + cp.w) >> 6;
  }
  if (w != pw) {  // leader
    for (int g = pw + 1; g < w; ++g) {  // gap fill (avg ~1.2 words)
      bitmap[g] = 0ull;
      prefix[g] = (uint32_t)i;
    }
    u64 bits = 1ull << (key & 63);
    int j = i + 1;
    while (j < n) {  // consecutive threads sharing my word (rare)
      int4 cj = coords[j];
      int kj = (cj.y * YD + cj.z) * XD + cj.w;
      if ((kj >> 6) != w) break;
      bits |= 1ull << (kj & 63);
      ++j;
    }
    bitmap[w] = bits;
    prefix[w] = (uint32_t)i;
  }
}

__global__ void __launch_bounds__(256) subm_conv(
    const float4* __restrict__ feats, const int4* __restrict__ coords,
    const float* __restrict__ weight, const uint32_t* __restrict__ prefix,
    const u64* __restrict__ bitmap, float* __restrict__ out,
    float* __restrict__ partial, int n) {
  __shared__ float wl[27 * 64];  // [k][c][o] = k*64 + c*16 + o
  __shared__ float sw[4][32];
  for (int t = threadIdx.x; t < 27 * 64; t += 256) wl[t] = weight[t];
  __syncthreads();

  // Bijective XCD-chunk swizzle: contiguous voxel ranges per XCD so the
  // sorted-key bitmap+prefix slice (~2.2MB) stays in the per-XCD 4MB L2.
  int B = gridDim.x;
  int q = B >> 3, r = B & 7;
  int xcd = blockIdx.x & 7, off = blockIdx.x >> 3;
  int sb = (xcd < r ? xcd * (q + 1) : r * (q + 1) + (xcd - r) * q) + off;
  int i = sb * 256 + (int)threadIdx.x;

  float acc[16];
#pragma unroll
  for (int o = 0; o < 16; o++) acc[o] = 0.f;

  if (i < n) {  // no early return: all threads join the BN epilogue
    int4 czyx = coords[i];
    int z = czyx.y, y = czyx.z, x = czyx.w;
    int key = (z * YD + y) * XD + x;

#pragma unroll
    for (int dz = -1; dz <= 1; dz++) {
      if ((unsigned)(z + dz) >= (unsigned)ZD) continue;
#pragma unroll
      for (int dy = -1; dy <= 1; dy++) {
        if ((unsigned)(y + dy) >= (unsigned)YD) continue;
        int nb = key + dz * YXD + dy * XD;  // dx = 0 neighbor key
        int base = nb - 1;
        int w0i = base >> 6;  // arithmetic shift: base=-1 -> -1 (safe read)
        u64 w0 = bitmap[w0i];
        u64 w1 = bitmap[w0i + 1];
        unsigned p = (unsigned)(base & 63);
        u64 win = (w0 >> p) | (p ? (w1 << (64 - p)) : 0ull);
        unsigned m = (unsigned)win & 7u;
        if (x == 0) m &= 6u;
        if (x == XD - 1) m &= 3u;
        if (!m) continue;
        uint32_t pre0 = prefix[w0i];      // lazy: only on hit (~1.11/voxel)
        uint32_t pre1 = prefix[w0i + 1];  // adjacent, L2-resident
        do {
          int b = __ffs(m) - 1;  // 0,1,2 -> dx = b-1
          m &= m - 1;
          int nk = base + b;
          int wi = nk >> 6;
          u64 word = (wi == w0i) ? w0 : w1;
          uint32_t pre = (wi == w0i) ? pre0 : pre1;
          int j = (int)pre + __popcll(word & ((1ull << (nk & 63)) - 1ull));
          float4 f = feats[j];
          const float* wp = &wl[((dz + 1) * 9 + (dy + 1) * 3 + b) * 64];
#pragma unroll
          for (int o = 0; o < 16; o++)
            acc[o] += f.x * wp[o] + f.y * wp[o + 16] + f.z * wp[o + 32] +
                      f.w * wp[o + 48];
        } while (m);
      }
    }

    float4* o4 = (float4*)(out + (size_t)i * 16);
    o4[0] = make_float4(acc[0], acc[1], acc[2], acc[3]);
    o4[1] = make_float4(acc[4], acc[5], acc[6], acc[7]);
    o4[2] = make_float4(acc[8], acc[9], acc[10], acc[11]);
    o4[3] = make_float4(acc[12], acc[13], acc[14], acc[15]);
  }

  // Fused BN partial reduction (inactive threads contribute acc==0).
  int lane = threadIdx.x & 63, wv = threadIdx.x >> 6;
#pragma unroll
  for (int o = 0; o < 16; o++) {
    float s = acc[o], qq = acc[o] * acc[o];
#pragma unroll
    for (int offx = 32; offx; offx >>= 1) {
      s += __shfl_xor(s, offx);
      qq += __shfl_xor(qq, offx);
    }
    if (lane == 0) {
      sw[wv][o] = s;
      sw[wv][16 + o] = qq;
    }
  }
  __syncthreads();
  if (threadIdx.x < 32) {
    float v = sw[0][threadIdx.x] + sw[1][threadIdx.x] + sw[2][threadIdx.x] +
              sw[3][threadIdx.x];
    partial[(size_t)blockIdx.x * 32 + threadIdx.x] = v;
  }
}

// Single block, 1024 threads, float4 loads: 8 lanes cover one 32-float row,
// 128 rows in flight per sweep -> ~13 iterations (R5's 256-thread scalar
// version did ~195 latency-serialized iterations = 51 us).
__global__ void __launch_bounds__(1024) bn_finalize(
    const float4* __restrict__ partial4, float* __restrict__ accum, int nb) {
  __shared__ float4 s4[1024];
  int t = threadIdx.x;
  int q = t & 7;        // float4 index within row (8 x float4 = 32 floats)
  int row0 = t >> 3;    // starting row, 128 rows in parallel
  float4 v = make_float4(0.f, 0.f, 0.f, 0.f);
  for (int b = row0; b < nb; b += 128) {
    float4 p = partial4[(size_t)b * 8 + q];
    v.x += p.x;
    v.y += p.y;
    v.z += p.z;
    v.w += p.w;
  }
  s4[t] = v;
  __syncthreads();
  for (int half = 64; half >= 1; half >>= 1) {
    if (row0 < half) {
      float4 o = s4[t + half * 8];
      v.x += o.x;
      v.y += o.y;
      v.z += o.z;
      v.w += o.w;
      s4[t] = v;
    }
    __syncthreads();
  }
  if (t < 8) ((float4*)accum)[t] = s4[t];
}

__global__ void __launch_bounds__(256) bn_apply(
    float* __restrict__ out, const float* __restrict__ accum,
    const float* __restrict__ gamma, const float* __restrict__ beta, int n4,
    float invN) {
  __shared__ float sa[16], sb[16];
  int t = threadIdx.x;
  if (t < 16) {
    float mu = accum[t] * invN;
    float var = accum[16 + t] * invN - mu * mu;
    float inv = rsqrtf(var + BN_EPS);
    float a = gamma[t] * inv;
    sa[t] = a;
    sb[t] = beta[t] - mu * a;
  }
  __syncthreads();
  int i = blockIdx.x * 256 + t;
  if (i >= n4) return;
  float4* p = (float4*)out;
  float4 v = p[i];
  int c0 = (i & 3) * 4;
  v.x = fmaxf(v.x * sa[c0 + 0] + sb[c0 + 0], 0.f);
  v.y = fmaxf(v.y * sa[c0 + 1] + sb[c0 + 1], 0.f);
  v.z = fmaxf(v.z * sa[c0 + 2] + sb[c0 + 2], 0.f);
  v.w = fmaxf(v.w * sa[c0 + 3] + sb[c0 + 3], 0.f);
  p[i] = v;
}

extern "C" void kernel_launch(void* const* d_in, const int* in_sizes, int n_in,
                              void* d_out, int out_size, void* d_ws,
                              size_t ws_size, hipStream_t stream) {
  const float4* feats = (const float4*)d_in[0];
  const int4* coords = (const int4*)d_in[1];
  const float* weight = (const float*)d_in[2];
  const float* gamma = (const float*)d_in[3];
  const float* beta = (const float*)d_in[4];
  int n = in_sizes[0] / 4;

  float* accum = (float*)d_ws;
  uint32_t* prefix = (uint32_t*)((char*)d_ws + 128);
  u64* bitmap = (u64*)((char*)d_ws + 128 + (size_t)BM_WORDS * 4);
  float* partial =
      (float*)((char*)d_ws + 128 + (size_t)BM_WORDS * 4 + (size_t)BM_WORDS * 8 + 8);

  int bb = (n + 255) / 256;
  hipLaunchKernelGGL(build_index, dim3(bb), dim3(256), 0, stream, coords,
                     prefix, bitmap, n);
  hipLaunchKernelGGL(subm_conv, dim3(bb), dim3(256), 0, stream, feats, coords,
                     weight, prefix, bitmap, (float*)d_out, partial, n);
  hipLaunchKernelGGL(bn_finalize, dim3(1), dim3(1024), 0, stream,
                     (const float4*)partial, accum, bb);
  int n4 = n * 4;
  hipLaunchKernelGGL(bn_apply, dim3((n4 + 255) / 256), dim3(256), 0, stream,
                     (float*)d_out, accum, gamma, beta, n4, 1.0f / n);
}

// Round 8
// 123.842 us; speedup vs baseline: 243.2457x; 1.0454x over previous
//
#include <hip/hip_runtime.h>
#include <stdint.h>

#define ZD 41
#define YD 1600
#define XD 1408
#define YXD (YD * XD)
#define NKEYS (ZD * YD * XD)     // 92,364,800 linear sites (divisible by 32)
#define ENT_WORDS (NKEYS / 32)   // 2,886,400 u64 entries {hi: bits32, lo: prefix}
#define BN_EPS 1e-3f

typedef unsigned long long u64;

// ---------------- ws layout ----------------
// [0,128)        accum: [0..15]=sum, [16..31]=sumsq (written by bn_finalize)
// [128,256)      pad (entry[-1] speculative read lands here; always masked out)
// [256, +ENT_WORDS*8)  entry[g]: hi32 = occupancy bits of sites [g*32,g*32+31],
//                      lo32 = # active keys with key < g*32  (merged rank index)
// [+16]          pad (entry[ENT_WORDS] speculative read; masked out)
// [then]         per-block BN partials [bid][0..15]=sum,[16..31]=sumsq

// Build merged entries with NO atomics: keys sorted ascending (np.unique), so
// thread i leads its 32-site granule iff granule(key[i-1]) differs. Leaders OR
// word-mates' bits and gap-fill left; tail past max key filled GRID-STRIDE
// (R4 lesson: single-thread tail = 30 ms).
__global__ void __launch_bounds__(256) build_index(
    const int4* __restrict__ coords, u64* __restrict__ entry, int n) {
  int i = blockIdx.x * blockDim.x + threadIdx.x;

  {  // parallel tail fill: bits=0, prefix=n
    int4 cl = coords[n - 1];
    int glast = (((cl.y * YD + cl.z) * XD + cl.w)) >> 5;
    int stride = gridDim.x * blockDim.x;
    for (int g = glast + 1 + i; g < ENT_WORDS; g += stride)
      entry[g] = (u64)(uint32_t)n;
  }

  if (i >= n) return;
  int4 c = coords[i];  // (0, z, y, x)
  int key = (c.y * YD + c.z) * XD + c.w;
  int g = key >> 5;

  int pkey = __shfl_up(key, 1);  // previous lane's key (same wave)
  if ((threadIdx.x & 63) == 0 && i > 0) {
    int4 cp = coords[i - 1];
    pkey = (cp.y * YD + cp.z) * XD + cp.w;
  }
  int pg = (i > 0) ? (pkey >> 5) : -1;

  if (g != pg) {  // leader
    for (int gg = pg + 1; gg < g; ++gg) entry[gg] = (u64)(uint32_t)i;  // gaps
    uint32_t bits = 1u << (key & 31);
    int j = i + 1;
    while (j < n) {
      int4 cj = coords[j];
      int kj = (cj.y * YD + cj.z) * XD + cj.w;
      if ((kj >> 5) != g) break;
      bits |= 1u << (kj & 31);
      ++j;
    }
    entry[g] = ((u64)bits << 32) | (uint32_t)i;
  }
}

__global__ void __launch_bounds__(256) subm_conv(
    const float4* __restrict__ feats, const int4* __restrict__ coords,
    const float* __restrict__ weight, const u64* __restrict__ entry,
    float* __restrict__ out, float* __restrict__ partial, int n) {
  __shared__ float wl[27 * 64];  // [k][c][o] = k*64 + c*16 + o
  __shared__ float swred[4][32];
  for (int t = threadIdx.x; t < 27 * 64; t += 256) wl[t] = weight[t];
  __syncthreads();

  // Bijective XCD-chunk swizzle: contiguous voxel ranges per XCD so the
  // entry-table slice (~2.9MB) stays in the per-XCD 4MB L2.
  int B = gridDim.x;
  int q = B >> 3, r = B & 7;
  int xcd = blockIdx.x & 7, off = blockIdx.x >> 3;
  int sb = (xcd < r ? xcd * (q + 1) : r * (q + 1) + (xcd - r) * q) + off;
  int i = sb * 256 + (int)threadIdx.x;

  float acc[16];
#pragma unroll
  for (int o = 0; o < 16; o++) acc[o] = 0.f;

  if (i < n) {
    int4 czyx = coords[i];
    int z = czyx.y, y = czyx.z, x = czyx.w;
    int key = (z * YD + y) * XD + x;

    // Self contribution (always present): coalesced feats[i], k=13 weights
    // (broadcast LDS read, conflict-free).
    {
      float4 fs = feats[i];
      const float* wp = &wl[13 * 64];
#pragma unroll
      for (int o = 0; o < 16; o++)
        acc[o] = fs.x * wp[o] + fs.y * wp[o + 16] + fs.z * wp[o + 32] +
                 fs.w * wp[o + 48];
    }

    // All 9 (dz,dy) windows issued up-front: 18 independent 8B loads ->
    // one 27-bit hit mask. Bit b = (dz+1)*9+(dy+1)*3+(dx+1) = kernel offset.
    unsigned mask27 = 0;
#pragma unroll
    for (int dzy = 0; dzy < 9; dzy++) {
      const int dz = dzy / 3 - 1, dy = dzy % 3 - 1;
      bool ok = ((unsigned)(z + dz) < (unsigned)ZD) &&
                ((unsigned)(y + dy) < (unsigned)YD);
      int base = key + dz * YXD + dy * XD - 1;
      int g0 = base >> 5;  // arithmetic shift: base=-1 -> -1 (pad region)
      u64 e0 = 0, e1 = 0;
      if (ok) {
        e0 = entry[g0];
        e1 = entry[g0 + 1];
      }
      u64 W = (e0 >> 32) | (e1 & 0xFFFFFFFF00000000ull);  // 64 occupancy bits
      unsigned m3 = (unsigned)(W >> (base & 31)) & 7u;
      mask27 |= m3 << (dzy * 3);
    }
    mask27 &= ~(1u << 13);                     // self handled above
    if (x == 0) mask27 &= ~0x1249249u;         // dx=-1 bits
    if (x == XD - 1) mask27 &= ~0x4924924u;    // dx=+1 bits

    // Rare extras (~0.11/voxel): entry reload is L1-hot; j = prefix + rank.
    while (mask27) {
      int b = __ffs(mask27) - 1;
      mask27 &= mask27 - 1;
      int dzy = (b * 11) >> 5;  // b/3 for b<27
      int rem = b - dzy * 3;
      int dzq = (dzy * 11) >> 5;  // dzy/3
      int dyr = dzy - dzq * 3;
      int s = key + (dzq - 1) * YXD + (dyr - 1) * XD + rem - 1;
      int gs = s >> 5;
      u64 e = entry[gs];
      int j = (int)(e & 0xFFFFFFFFull) +
              __popc((uint32_t)(e >> 32) & ((1u << (s & 31)) - 1u));
      float4 f = feats[j];
      const float* wp = &wl[b * 64];
#pragma unroll
      for (int o = 0; o < 16; o++)
        acc[o] += f.x * wp[o] + f.y * wp[o + 16] + f.z * wp[o + 32] +
                  f.w * wp[o + 48];
    }

    float4* o4 = (float4*)(out + (size_t)i * 16);
    o4[0] = make_float4(acc[0], acc[1], acc[2], acc[3]);
    o4[1] = make_float4(acc[4], acc[5], acc[6], acc[7]);
    o4[2] = make_float4(acc[8], acc[9], acc[10], acc[11]);
    o4[3] = make_float4(acc[12], acc[13], acc[14], acc[15]);
  }

  // Fused BN partial reduction (inactive threads contribute acc==0).
  int lane = threadIdx.x & 63, wv = threadIdx.x >> 6;
#pragma unroll
  for (int o = 0; o < 16; o++) {
    float s = acc[o], qq = acc[o] * acc[o];
#pragma unroll
    for (int offx = 32; offx; offx >>= 1) {
      s += __shfl_xor(s, offx);
      qq += __shfl_xor(qq, offx);
    }
    if (lane == 0) {
      swred[wv][o] = s;
      swred[wv][16 + o] = qq;
    }
  }
  __syncthreads();
  if (threadIdx.x < 32) {
    float v = swred[0][threadIdx.x] + swred[1][threadIdx.x] +
              swred[2][threadIdx.x] + swred[3][threadIdx.x];
    partial[(size_t)blockIdx.x * 32 + threadIdx.x] = v;
  }
}

// Single block, 1024 threads, float4 loads: 8 lanes per 32-float row,
// 128 rows in flight (R5 lesson: 256-thread scalar version = 51 us).
__global__ void __launch_bounds__(1024) bn_finalize(
    const float4* __restrict__ partial4, float* __restrict__ accum, int nb) {
  __shared__ float4 s4[1024];
  int t = threadIdx.x;
  int q = t & 7;
  int row0 = t >> 3;
  float4 v = make_float4(0.f, 0.f, 0.f, 0.f);
  for (int b = row0; b < nb; b += 128) {
    float4 p = partial4[(size_t)b * 8 + q];
    v.x += p.x;
    v.y += p.y;
    v.z += p.z;
    v.w += p.w;
  }
  s4[t] = v;
  __syncthreads();
  for (int half = 64; half >= 1; half >>= 1) {
    if (row0 < half) {
      float4 o = s4[t + half * 8];
      v.x += o.x;
      v.y += o.y;
      v.z += o.z;
      v.w += o.w;
      s4[t] = v;
    }
    __syncthreads();
  }
  if (t < 8) ((float4*)accum)[t] = s4[t];
}

__global__ void __launch_bounds__(256) bn_apply(
    float* __restrict__ out, const float* __restrict__ accum,
    const float* __restrict__ gamma, const float* __restrict__ beta, int n4,
    float invN) {
  __shared__ float sa[16], sb[16];
  int t = threadIdx.x;
  if (t < 16) {
    float mu = accum[t] * invN;
    float var = accum[16 + t] * invN - mu * mu;
    float inv = rsqrtf(var + BN_EPS);
    float a = gamma[t] * inv;
    sa[t] = a;
    sb[t] = beta[t] - mu * a;
  }
  __syncthreads();
  int i = blockIdx.x * 256 + t;
  if (i >= n4) return;
  float4* p = (float4*)out;
  float4 v = p[i];
  int c0 = (i & 3) * 4;
  v.x = fmaxf(v.x * sa[c0 + 0] + sb[c0 + 0], 0.f);
  v.y = fmaxf(v.y * sa[c0 + 1] + sb[c0 + 1], 0.f);
  v.z = fmaxf(v.z * sa[c0 + 2] + sb[c0 + 2], 0.f);
  v.w = fmaxf(v.w * sa[c0 + 3] + sb[c0 + 3], 0.f);
  p[i] = v;
}

extern "C" void kernel_launch(void* const* d_in, const int* in_sizes, int n_in,
                              void* d_out, int out_size, void* d_ws,
                              size_t ws_size, hipStream_t stream) {
  const float4* feats = (const float4*)d_in[0];
  const int4* coords = (const int4*)d_in[1];
  const float* weight = (const float*)d_in[2];
  const float* gamma = (const float*)d_in[3];
  const float* beta = (const float*)d_in[4];
  int n = in_sizes[0] / 4;

  float* accum = (float*)d_ws;
  u64* entry = (u64*)((char*)d_ws + 256);
  float* partial = (float*)((char*)d_ws + 256 + (size_t)ENT_WORDS * 8 + 16);

  int bb = (n + 255) / 256;
  hipLaunchKernelGGL(build_index, dim3(bb), dim3(256), 0, stream, coords,
                     entry, n);
  hipLaunchKernelGGL(subm_conv, dim3(bb), dim3(256), 0, stream, feats, coords,
                     weight, entry, (float*)d_out, partial, n);
  hipLaunchKernelGGL(bn_finalize, dim3(1), dim3(1024), 0, stream,
                     (const float4*)partial, accum, bb);
  int n4 = n * 4;
  hipLaunchKernelGGL(bn_apply, dim3((n4 + 255) / 256), dim3(256), 0, stream,
                     (float*)d_out, accum, gamma, beta, n4, 1.0f / n);
}